// Round 7
// baseline (186.622 us; speedup 1.0000x reference)
//
#include <hip/hip_runtime.h>
#include <math.h>

#define HP 258
#define RPAD 320              // padded rows for bf16 operand buffers
#define BSTR 328              // bf16 row stride (656B, 16B-aligned)
#define NPIX (HP*HP)          // 66564
#define NPB  (RPAD*BSTR)      // 104960 bf16 elems per channel
#define PTOT (RPAD*BSTR)
#define C30 30
#define TOT (C30*NPIX)
#define LOGW 64

typedef __bf16 bf16x8 __attribute__((ext_vector_type(8)));
typedef float  f32x4  __attribute__((ext_vector_type(4)));
typedef unsigned short ushort;
typedef unsigned short ushort8 __attribute__((ext_vector_type(8)));

static __device__ inline ushort f2bf(float f){
  __bf16 h = (__bf16)f;
  return __builtin_bit_cast(ushort, h);
}

// ---------------- build padded fc channels (30 distinct, each x2 in ref) ----
__global__ void build_fc_k(const float* __restrict__ logits,
                           float* __restrict__ xp, ushort* __restrict__ xpbf){
  int p = blockIdx.x*256 + threadIdx.x;
  if (p >= PTOT) return;
  int h = p / BSTR, w = p % BSTR;
  if (h >= HP || w >= HP){
    #pragma unroll
    for (int c=0;c<C30;c++) xpbf[(size_t)c*NPB+p] = 0;
    return;
  }
  int pd = h*HP + w;
  if (h==0 || h==HP-1 || w==0 || w==HP-1){
    ushort one = f2bf(1.0f);
    #pragma unroll
    for (int c=0;c<C30;c++){ xp[(size_t)c*NPIX+pd] = 1.0f; xpbf[(size_t)c*NPB+p] = one; }
    return;
  }
  int oh = h-1, ow = w-1;
  float fy = 0.25f*oh - 0.375f;
  float fx = 0.25f*ow - 0.375f;
  float y0f = floorf(fy), x0f = floorf(fx);
  float ty = fy - y0f, tx = fx - x0f;
  int y0 = max(0, (int)y0f), y1 = min(LOGW-1, (int)y0f + 1);
  int x0 = max(0, (int)x0f), x1 = min(LOGW-1, (int)x0f + 1);
  float s[6];
  float m = -3.402823466e+38f;
  #pragma unroll
  for (int c=0;c<6;c++){
    const float* pl = logits + c*LOGW*LOGW;
    float v00 = pl[y0*LOGW + x0], v01 = pl[y0*LOGW + x1];
    float v10 = pl[y1*LOGW + x0], v11 = pl[y1*LOGW + x1];
    float a = v00 + (v01 - v00)*tx;
    float b = v10 + (v11 - v10)*tx;
    float v = a + (b - a)*ty;
    s[c] = v; m = fmaxf(m, v);
  }
  float sum = 0.0f;
  #pragma unroll
  for (int c=0;c<6;c++){ s[c] = expf(s[c]-m); sum += s[c]; }
  float inv = 1.0f/sum;
  #pragma unroll
  for (int c=0;c<6;c++) s[c] *= inv;
  #pragma unroll
  for (int c=0;c<C30;c++){
    int i = c/5, r = c%5;
    int j = r + (r>=i ? 1 : 0);
    float d = 0.5f*(s[i]-s[j]);
    float v = fmaxf(d, 0.0f);
    xp[(size_t)c*NPIX+pd]  = v;
    xpbf[(size_t)c*NPB+p] = f2bf(v);
  }
}

// ------- transpose padded bf16: dst[i][j] = src[j][i], i,j in [0,RPAD) ------
__global__ void transpose_k(const ushort* __restrict__ src, ushort* __restrict__ dst){
  __shared__ ushort t[32][33];
  int ch = blockIdx.z;
  const ushort* s = src + (size_t)ch*NPB;
  ushort*       d = dst + (size_t)ch*NPB;
  int j0 = blockIdx.x*32;
  int i0 = blockIdx.y*32;
  #pragma unroll
  for (int k=0;k<4;k++){
    int jj = threadIdx.y + k*8, ii = threadIdx.x;
    t[jj][ii] = s[(size_t)(j0+jj)*BSTR + (i0+ii)];
  }
  __syncthreads();
  #pragma unroll
  for (int k=0;k<4;k++){
    int ii = threadIdx.y + k*8, jj = threadIdx.x;
    d[(size_t)(i0+ii)*BSTR + (j0+jj)] = t[jj][ii];
  }
}

// ------------- combined max+avg 3x3 pool + pad, fp32 in -> padded bf16 ------
__global__ void pool_both_k(const float* __restrict__ X,
                            ushort* __restrict__ pmax, ushort* __restrict__ pavg){
  int c = blockIdx.y;
  int p = blockIdx.x*256 + threadIdx.x;
  if (p >= PTOT) return;
  int h = p / BSTR, w = p % BSTR;
  size_t ob = (size_t)c*NPB + p;
  if (h >= HP || w >= HP){ pmax[ob] = 0; pavg[ob] = 0; return; }
  if (h==0 || h==HP-1 || w==0 || w==HP-1){
    ushort one = f2bf(1.0f);
    pmax[ob] = one; pavg[ob] = one;
    return;
  }
  const float* s = X + (size_t)c*NPIX;
  float mv = -3.402823466e+38f, av = 0.0f;
  #pragma unroll
  for (int dy=-1;dy<=1;dy++){
    const float* r = s + (size_t)(h+dy)*HP + (w-1);
    float a = r[0], b = r[1], d = r[2];
    mv = fmaxf(mv, fmaxf(fmaxf(a,b),d));
    av += a+b+d;
  }
  pmax[ob] = f2bf(mv);
  pavg[ob] = f2bf(av*(1.0f/9.0f));
}

// ---------------- single 3x3 max pool + pad, fp32 in -> padded bf16 ---------
__global__ void pool_max_k(const float* __restrict__ X, ushort* __restrict__ out){
  int c = blockIdx.y;
  int p = blockIdx.x*256 + threadIdx.x;
  if (p >= PTOT) return;
  int h = p / BSTR, w = p % BSTR;
  size_t ob = (size_t)c*NPB + p;
  if (h >= HP || w >= HP){ out[ob] = 0; return; }
  if (h==0 || h==HP-1 || w==0 || w==HP-1){ out[ob] = f2bf(1.0f); return; }
  const float* s = X + (size_t)c*NPIX;
  float mv = -3.402823466e+38f;
  #pragma unroll
  for (int dy=-1;dy<=1;dy++){
    const float* r = s + (size_t)(h+dy)*HP + (w-1);
    mv = fmaxf(mv, fmaxf(fmaxf(r[0],r[1]),r[2]));
  }
  out[ob] = f2bf(mv);
}

// ---------------- MFMA matmul core (branch-free staging, BK=64 + 32 tail) ---
#define MM_PROLOGUE()                                                          \
  int tid = threadIdx.x;                                                       \
  int lane = tid & 63, wv = tid >> 6;                                          \
  int wr = (wv >> 1)*32, wc = (wv & 1)*32;                                     \
  int rowBase = blockIdx.x*64, colBase = blockIdx.y*64;                        \
  int l15 = lane & 15, lq = lane >> 4;                                         \
  f32x4 acc00 = {0.f,0.f,0.f,0.f}, acc01 = acc00, acc10 = acc00, acc11 = acc00;\
  int srow = tid >> 3, sc8 = tid & 7;

#define MM_MFMA_HALF(KK)                                                       \
  {                                                                            \
    bf16x8 a0 = __builtin_bit_cast(bf16x8, *(const ushort8*)(&As[(wr      + l15)*72 + (KK) + lq*8])); \
    bf16x8 a1 = __builtin_bit_cast(bf16x8, *(const ushort8*)(&As[(wr + 16 + l15)*72 + (KK) + lq*8])); \
    bf16x8 b0 = __builtin_bit_cast(bf16x8, *(const ushort8*)(&Bs[(wc      + l15)*72 + (KK) + lq*8])); \
    bf16x8 b1 = __builtin_bit_cast(bf16x8, *(const ushort8*)(&Bs[(wc + 16 + l15)*72 + (KK) + lq*8])); \
    acc00 = __builtin_amdgcn_mfma_f32_16x16x32_bf16(a0, b0, acc00, 0, 0, 0);   \
    acc01 = __builtin_amdgcn_mfma_f32_16x16x32_bf16(a0, b1, acc01, 0, 0, 0);   \
    acc10 = __builtin_amdgcn_mfma_f32_16x16x32_bf16(a1, b0, acc10, 0, 0, 0);   \
    acc11 = __builtin_amdgcn_mfma_f32_16x16x32_bf16(a1, b1, acc11, 0, 0, 0);   \
  }

// --- mm_store: C(fp32 dense) = A @ B^T; COLPART adds per-block column sums --
template<int COLPART>
__global__ __launch_bounds__(256) void mm_store_k(const ushort* __restrict__ A,
                                                  const ushort* __restrict__ BT,
                                                  float* __restrict__ C,
                                                  float* __restrict__ colpart){
  __shared__ ushort As[64*72];
  __shared__ ushort Bs[64*72];
  __shared__ float colred[8*64];
  int ch = blockIdx.z;
  MM_PROLOGUE();
  const ushort* Ab = A  + (size_t)ch*NPB + (size_t)rowBase*BSTR;
  const ushort* Bb = BT + (size_t)ch*NPB + (size_t)colBase*BSTR;
  const ushort* apt = Ab + (size_t)srow*BSTR + sc8*8;
  const ushort* bpt = Bb + (size_t)srow*BSTR + sc8*8;
  float*        Cb = C  + (size_t)ch*NPIX;
  for (int k0 = 0; k0 < 256; k0 += 64){
    *(ushort8*)(&As[srow*72 + sc8*8])      = *(const ushort8*)(apt + k0);
    *(ushort8*)(&As[(srow+32)*72 + sc8*8]) = *(const ushort8*)(apt + (size_t)32*BSTR + k0);
    *(ushort8*)(&Bs[srow*72 + sc8*8])      = *(const ushort8*)(bpt + k0);
    *(ushort8*)(&Bs[(srow+32)*72 + sc8*8]) = *(const ushort8*)(bpt + (size_t)32*BSTR + k0);
    __syncthreads();
    MM_MFMA_HALF(0);
    MM_MFMA_HALF(32);
    __syncthreads();
  }
  {  // tail: k = 256..287 (zero pad beyond 258)
    int row4 = tid >> 2, c84 = tid & 3;
    *(ushort8*)(&As[row4*72 + c84*8]) = *(const ushort8*)(Ab + (size_t)row4*BSTR + 256 + c84*8);
    *(ushort8*)(&Bs[row4*72 + c84*8]) = *(const ushort8*)(Bb + (size_t)row4*BSTR + 256 + c84*8);
    __syncthreads();
    MM_MFMA_HALF(0);
  }
  auto store = [&](f32x4 v, int r0, int c0){
    if (c0 < HP){
      #pragma unroll
      for (int r=0;r<4;r++){
        int rr = r0 + r;
        if (rr < HP) Cb[(size_t)rr*HP + c0] = v[r];
      }
    }
  };
  store(acc00, rowBase + wr +      lq*4, colBase + wc +      l15);
  store(acc01, rowBase + wr +      lq*4, colBase + wc + 16 + l15);
  store(acc10, rowBase + wr + 16 + lq*4, colBase + wc +      l15);
  store(acc11, rowBase + wr + 16 + lq*4, colBase + wc + 16 + l15);
  if (COLPART){
    // deterministic per-block column sums of acc over the 64 rows.
    // pad rows of A are zero -> zero acc -> no contamination.
    __syncthreads();
    int slot = (wv>>1)*4 + lq;
    float s0 = 0.0f, s1 = 0.0f;
    #pragma unroll
    for (int r=0;r<4;r++){ s0 += acc00[r] + acc10[r]; s1 += acc01[r] + acc11[r]; }
    colred[slot*64 + wc +      l15] = s0;
    colred[slot*64 + wc + 16 + l15] = s1;
    __syncthreads();
    if (tid < 64){
      float cs = 0.0f;
      #pragma unroll
      for (int s=0;s<8;s++) cs += colred[s*64 + tid];
      colpart[((size_t)ch*5 + blockIdx.x)*320 + colBase + tid] = cs;
    }
  }
}

// ------- mm_absred: acc = A @ (±B); part += |operand - acc| (no C write) ----
template<int NEGB>
__global__ __launch_bounds__(256) void mm_absred_k(const ushort* __restrict__ A,
                                                   const ushort* __restrict__ BT,
                                                   const float* __restrict__ XPop,
                                                   double* __restrict__ part){
  __shared__ ushort As[64*72];
  __shared__ ushort Bs[64*72];
  __shared__ double red[256];
  int ch = blockIdx.z;
  MM_PROLOGUE();
  const ushort* Ab = A  + (size_t)ch*NPB + (size_t)rowBase*BSTR;
  const ushort* Bb = BT + (size_t)ch*NPB + (size_t)colBase*BSTR;
  const ushort* apt = Ab + (size_t)srow*BSTR + sc8*8;
  const ushort* bpt = Bb + (size_t)srow*BSTR + sc8*8;
  const float*  Ob = XPop + (size_t)ch*NPIX;
  ushort one = f2bf(1.0f);
  auto fixB = [&](ushort8 t8, int brow, int kbase)->ushort8{
    if (!NEGB) return t8;
    if (brow >= HP) return t8;
    #pragma unroll
    for (int i=0;i<8;i++){
      int kk = kbase + i;
      if (kk < HP)
        t8[i] = (brow==0 || brow==HP-1 || kk==0 || kk==HP-1) ? one : (ushort)(t8[i] ^ 0x8000);
    }
    return t8;
  };
  for (int k0 = 0; k0 < 256; k0 += 64){
    *(ushort8*)(&As[srow*72 + sc8*8])      = *(const ushort8*)(apt + k0);
    *(ushort8*)(&As[(srow+32)*72 + sc8*8]) = *(const ushort8*)(apt + (size_t)32*BSTR + k0);
    *(ushort8*)(&Bs[srow*72 + sc8*8])      = fixB(*(const ushort8*)(bpt + k0), colBase + srow, k0 + sc8*8);
    *(ushort8*)(&Bs[(srow+32)*72 + sc8*8]) = fixB(*(const ushort8*)(bpt + (size_t)32*BSTR + k0), colBase + srow + 32, k0 + sc8*8);
    __syncthreads();
    MM_MFMA_HALF(0);
    MM_MFMA_HALF(32);
    __syncthreads();
  }
  {
    int row4 = tid >> 2, c84 = tid & 3;
    *(ushort8*)(&As[row4*72 + c84*8]) = *(const ushort8*)(Ab + (size_t)row4*BSTR + 256 + c84*8);
    *(ushort8*)(&Bs[row4*72 + c84*8]) = fixB(*(const ushort8*)(Bb + (size_t)row4*BSTR + 256 + c84*8), colBase + row4, 256 + c84*8);
    __syncthreads();
    MM_MFMA_HALF(0);
  }
  double local = 0.0;
  auto addq = [&](f32x4 v, int r0, int c0){
    if (c0 < HP){
      #pragma unroll
      for (int r=0;r<4;r++){
        int rr = r0 + r;
        if (rr < HP){
          float o = Ob[(size_t)rr*HP + c0];
          if (NEGB) o = (rr==0||rr==HP-1||c0==0||c0==HP-1) ? 1.0f : -o;
          local += (double)fabsf(o - v[r]);
        }
      }
    }
  };
  addq(acc00, rowBase + wr +      lq*4, colBase + wc +      l15);
  addq(acc01, rowBase + wr +      lq*4, colBase + wc + 16 + l15);
  addq(acc10, rowBase + wr + 16 + lq*4, colBase + wc +      l15);
  addq(acc11, rowBase + wr + 16 + lq*4, colBase + wc + 16 + l15);
  red[tid] = local;
  __syncthreads();
  for (int s=128; s>0; s>>=1){ if (tid<s) red[tid]+=red[tid+s]; __syncthreads(); }
  if (tid==0) part[(size_t)blockIdx.z*25 + blockIdx.y*5 + blockIdx.x] = red[0];
}

// ------- cm[c][w] = (sum_bx colpart_y - colsum x)/258 -----------------------
__global__ void cmcomb_k(const float* __restrict__ colpart, const float* __restrict__ xsrc,
                         float* __restrict__ cm){
  int c = blockIdx.y;
  int w = blockIdx.x*256 + threadIdx.x;
  if (w >= HP) return;
  const float* xb = xsrc + (size_t)c*NPIX;
  float xs = 0.0f;
  for (int r=0;r<HP;r++) xs += xb[(size_t)r*HP + w];
  float ys = 0.0f;
  #pragma unroll
  for (int bx=0;bx<5;bx++) ys += colpart[((size_t)c*5 + bx)*320 + w];
  cm[c*HP + w] = (ys - xs) / (float)HP;
}

// ------- fused rectify + avg-pool: x1 = rect(x,y,cm); out = poolpad(x1) -----
__global__ void rect_pool_avg_k(const float* __restrict__ x, const float* __restrict__ y,
                                const float* __restrict__ cm,
                                float* __restrict__ x1, ushort* __restrict__ out){
  __shared__ float rect[34][35];
  int c = blockIdx.z;
  int r0 = blockIdx.y*32, c0 = blockIdx.x*32;
  int tid = threadIdx.x;
  const float* xb = x + (size_t)c*NPIX;
  const float* yb = y + (size_t)c*NPIX;
  // compute rectified values on 34x34 halo tile
  for (int idx = tid; idx < 34*34; idx += 256){
    int lr = idx/34, lc = idx%34;
    int h = r0 - 1 + lr, w = c0 - 1 + lc;
    float v = 0.0f;
    if (h >= 0 && h < HP && w >= 0 && w < HP){
      float xv = xb[(size_t)h*HP + w];
      float off = yb[(size_t)h*HP + w] - xv - cm[c*HP + w];
      v = xv + fmaxf(off, 0.0f);
    }
    rect[lr][lc] = v;
  }
  __syncthreads();
  for (int idx = tid; idx < 32*32; idx += 256){
    int lr = idx/32, lc = idx%32;
    int h = r0 + lr, w = c0 + lc;
    if (w >= BSTR || h >= RPAD) continue;
    bool vpix = (h < HP && w < HP);
    if (vpix) x1[(size_t)c*NPIX + (size_t)h*HP + w] = rect[lr+1][lc+1];
    ushort o;
    if (!vpix) o = 0;
    else if (h==0 || h==HP-1 || w==0 || w==HP-1) o = f2bf(1.0f);
    else {
      float av = (rect[lr][lc]   + rect[lr][lc+1]   + rect[lr][lc+2])
               + (rect[lr+1][lc] + rect[lr+1][lc+1] + rect[lr+1][lc+2])
               + (rect[lr+2][lc] + rect[lr+2][lc+1] + rect[lr+2][lc+2]);
      o = f2bf(av*(1.0f/9.0f));
    }
    out[(size_t)c*NPB + (size_t)h*BSTR + w] = o;
  }
}

// ------- per-pixel inv-norm over 30 ch (x2 dup); write scaled padded bf16 ---
__global__ void invnorm_scale_k(const float* __restrict__ oper, ushort* __restrict__ An){
  int p = blockIdx.x*256 + threadIdx.x;
  if (p >= PTOT) return;
  int h = p / BSTR, w = p % BSTR;
  if (h >= HP || w >= HP){
    #pragma unroll
    for (int c=0;c<C30;c++) An[(size_t)c*NPB+p] = 0;
    return;
  }
  int pd = h*HP + w;
  float v[C30];
  float ss = 0.0f;
  #pragma unroll
  for (int c=0;c<C30;c++){ v[c] = oper[(size_t)c*NPIX+pd]; ss = fmaf(v[c],v[c],ss); }
  float n = sqrtf(2.0f*ss);
  float inv = 1.0f / fmaxf(n, 1e-12f);
  #pragma unroll
  for (int c=0;c<C30;c++) An[(size_t)c*NPB+p] = f2bf(v[c]*inv);
}

// ------- fused rectify + inv-norm + scaled padded bf16 A write --------------
__global__ void rectify_invnorm_scale_k(const float* __restrict__ x, const float* __restrict__ y,
                                        const float* __restrict__ cm, ushort* __restrict__ An){
  int p = blockIdx.x*256 + threadIdx.x;
  if (p >= PTOT) return;
  int h = p / BSTR, w = p % BSTR;
  if (h >= HP || w >= HP){
    #pragma unroll
    for (int c=0;c<C30;c++) An[(size_t)c*NPB+p] = 0;
    return;
  }
  int pd = h*HP + w;
  float v[C30];
  float ss = 0.0f;
  #pragma unroll
  for (int c=0;c<C30;c++){
    float xv = x[(size_t)c*NPIX + pd];
    float off = y[(size_t)c*NPIX + pd] - xv - cm[c*HP + w];
    float vv = xv + fmaxf(off, 0.0f);
    v[c] = vv;
    ss = fmaf(vv, vv, ss);
  }
  float n = sqrtf(2.0f*ss);
  float inv = 1.0f / fmaxf(n, 1e-12f);
  #pragma unroll
  for (int c=0;c<C30;c++) An[(size_t)c*NPB+p] = f2bf(v[c]*inv);
}

// ---------------- final: |2*(S0 - S1)| + base_loss --------------------------
__global__ void finalize_k(const double* __restrict__ part,
                           const float* __restrict__ base, float* __restrict__ out){
  __shared__ double s0[256], s1[256];
  int tid = threadIdx.x;
  double l0=0.0, l1=0.0;
  for (int i=tid;i<750;i+=256){ l0 += part[i]; l1 += part[750+i]; }
  s0[tid]=l0; s1[tid]=l1; __syncthreads();
  for (int s=128;s>0;s>>=1){ if (tid<s){ s0[tid]+=s0[tid+s]; s1[tid]+=s1[tid+s]; } __syncthreads(); }
  if (tid==0){
    out[0] = (float)(fabs(2.0*(s0[0]-s1[0])) + (double)base[0]);
  }
}

extern "C" void kernel_launch(void* const* d_in, const int* in_sizes, int n_in,
                              void* d_out, int out_size, void* d_ws, size_t ws_size,
                              hipStream_t stream){
  const float* logits = (const float*)d_in[0];
  const float* base   = (const float*)d_in[1];
  float* out = (float*)d_out;

  char* ws = (char*)d_ws;
  size_t off = 0;
  auto alloc = [&](size_t bytes)->char*{
    char* p = ws + off; off = (off + bytes + 255) & ~(size_t)255; return p;
  };
  double* part    = (double*)alloc(1500*sizeof(double));
  float*  cm      = (float*) alloc((size_t)C30*HP*sizeof(float));
  float*  colpart = (float*) alloc((size_t)C30*5*320*sizeof(float));
  float*  XP      = (float*) alloc((size_t)TOT*sizeof(float));
  ushort* BF0     = (ushort*)alloc((size_t)C30*NPB*sizeof(ushort));
  ushort* BFT     = (ushort*)alloc((size_t)C30*NPB*sizeof(ushort));
  ushort* BF1     = (ushort*)alloc((size_t)C30*NPB*sizeof(ushort));
  ushort* BF2     = (ushort*)alloc((size_t)C30*NPB*sizeof(ushort));
  float*  F1      = (float*) alloc((size_t)TOT*sizeof(float));
  float*  X1      = (float*) alloc((size_t)TOT*sizeof(float));
  (void)ws_size; (void)in_sizes; (void)n_in; (void)out_size;

  dim3 mmGrid((HP+63)/64, (HP+63)/64, C30);          // 5 x 5 x 30
  dim3 trGrid(RPAD/32, RPAD/32, C30);                // 10 x 10 x 30
  dim3 padGrid((PTOT+255)/256, C30);
  dim3 cmGrid((HP+255)/256, C30);                    // 2 x 30
  dim3 rpGrid((BSTR+31)/32, RPAD/32, C30);           // 11 x 10 x 30
  int pb = (PTOT+255)/256;

  build_fc_k<<<pb,256,0,stream>>>(logits, XP, BF0);
  transpose_k<<<trGrid,dim3(32,8),0,stream>>>(BF0, BFT);
  pool_both_k<<<padGrid,256,0,stream>>>(XP, BF1, BF2);   // max -> BF1, avg -> BF2

  // ---- opening ----
  mm_store_k<0><<<mmGrid,256,0,stream>>>(BF1, BFT, F1, nullptr);   // C1
  pool_max_k<<<padGrid,256,0,stream>>>(F1, BF0);                   // BF0 free
  mm_store_k<0><<<mmGrid,256,0,stream>>>(BF0, BFT, F1, nullptr);   // operated_open
  invnorm_scale_k<<<pb,256,0,stream>>>(F1, BF1);                   // An
  mm_absred_k<1><<<mmGrid,256,0,stream>>>(BF1, BFT, XP, part);

  // ---- dilation ----
  mm_store_k<1><<<mmGrid,256,0,stream>>>(BF2, BFT, F1, colpart);   // y1 + col sums
  cmcomb_k<<<cmGrid,256,0,stream>>>(colpart, XP, cm);              // cm1
  rect_pool_avg_k<<<rpGrid,256,0,stream>>>(XP, F1, cm, X1, BF2);   // x1 + avgpool(x1)
  mm_store_k<1><<<mmGrid,256,0,stream>>>(BF2, BFT, F1, colpart);   // y2 + col sums
  cmcomb_k<<<cmGrid,256,0,stream>>>(colpart, X1, cm);              // cm2
  rectify_invnorm_scale_k<<<pb,256,0,stream>>>(X1, F1, cm, BF1);   // An2
  mm_absred_k<0><<<mmGrid,256,0,stream>>>(BF1, BFT, XP, part + 750);

  finalize_k<<<1,256,0,stream>>>(part, base, out);
}

// Round 8
// 166.912 us; speedup vs baseline: 1.1181x; 1.1181x over previous
//
#include <hip/hip_runtime.h>
#include <math.h>

#define HP 258
#define RPAD 320              // padded rows for bf16 operand buffers
#define BSTR 328              // bf16 row stride (656B, 16B-aligned)
#define NPIX (HP*HP)          // 66564
#define NPB  (RPAD*BSTR)      // 104960 bf16 elems per channel
#define PTOT (RPAD*BSTR)
#define C30 30
#define TOT (C30*NPIX)
#define LOGW 64
#define PBLK 410              // ceil(PTOT/256)

typedef __bf16 bf16x8 __attribute__((ext_vector_type(8)));
typedef float  f32x4  __attribute__((ext_vector_type(4)));
typedef unsigned short ushort;
typedef unsigned short ushort8 __attribute__((ext_vector_type(8)));

static __device__ inline ushort f2bf(float f){
  __bf16 h = (__bf16)f;
  return __builtin_bit_cast(ushort, h);
}

// ---------------- build padded fc channels (30 distinct, each x2 in ref) ----
__global__ void build_fc_k(const float* __restrict__ logits,
                           float* __restrict__ xp, ushort* __restrict__ xpbf){
  int p = blockIdx.x*256 + threadIdx.x;
  if (p >= PTOT) return;
  int h = p / BSTR, w = p % BSTR;
  if (h >= HP || w >= HP){
    #pragma unroll
    for (int c=0;c<C30;c++) xpbf[(size_t)c*NPB+p] = 0;
    return;
  }
  int pd = h*HP + w;
  if (h==0 || h==HP-1 || w==0 || w==HP-1){
    ushort one = f2bf(1.0f);
    #pragma unroll
    for (int c=0;c<C30;c++){ xp[(size_t)c*NPIX+pd] = 1.0f; xpbf[(size_t)c*NPB+p] = one; }
    return;
  }
  int oh = h-1, ow = w-1;
  float fy = 0.25f*oh - 0.375f;
  float fx = 0.25f*ow - 0.375f;
  float y0f = floorf(fy), x0f = floorf(fx);
  float ty = fy - y0f, tx = fx - x0f;
  int y0 = max(0, (int)y0f), y1 = min(LOGW-1, (int)y0f + 1);
  int x0 = max(0, (int)x0f), x1 = min(LOGW-1, (int)x0f + 1);
  float s[6];
  float m = -3.402823466e+38f;
  #pragma unroll
  for (int c=0;c<6;c++){
    const float* pl = logits + c*LOGW*LOGW;
    float v00 = pl[y0*LOGW + x0], v01 = pl[y0*LOGW + x1];
    float v10 = pl[y1*LOGW + x0], v11 = pl[y1*LOGW + x1];
    float a = v00 + (v01 - v00)*tx;
    float b = v10 + (v11 - v10)*tx;
    float v = a + (b - a)*ty;
    s[c] = v; m = fmaxf(m, v);
  }
  float sum = 0.0f;
  #pragma unroll
  for (int c=0;c<6;c++){ s[c] = expf(s[c]-m); sum += s[c]; }
  float inv = 1.0f/sum;
  #pragma unroll
  for (int c=0;c<6;c++) s[c] *= inv;
  #pragma unroll
  for (int c=0;c<C30;c++){
    int i = c/5, r = c%5;
    int j = r + (r>=i ? 1 : 0);
    float d = 0.5f*(s[i]-s[j]);
    float v = fmaxf(d, 0.0f);
    xp[(size_t)c*NPIX+pd]  = v;
    xpbf[(size_t)c*NPB+p] = f2bf(v);
  }
}

// ---- fused: [bx<PBLK] max+avg pool of XP -> bf16 | [else] transpose xpbf ---
__global__ void trpool_k(const ushort* __restrict__ xpbf, ushort* __restrict__ bft,
                         const float* __restrict__ X,
                         ushort* __restrict__ pmax, ushort* __restrict__ pavg){
  __shared__ ushort t[32][33];
  int c = blockIdx.y;
  int tid = threadIdx.x;
  if (blockIdx.x < PBLK){
    int p = blockIdx.x*256 + tid;
    if (p >= PTOT) return;
    int h = p / BSTR, w = p % BSTR;
    size_t ob = (size_t)c*NPB + p;
    if (h >= HP || w >= HP){ pmax[ob] = 0; pavg[ob] = 0; return; }
    if (h==0 || h==HP-1 || w==0 || w==HP-1){
      ushort one = f2bf(1.0f);
      pmax[ob] = one; pavg[ob] = one;
      return;
    }
    const float* s = X + (size_t)c*NPIX;
    float mv = -3.402823466e+38f, av = 0.0f;
    #pragma unroll
    for (int dy=-1;dy<=1;dy++){
      const float* r = s + (size_t)(h+dy)*HP + (w-1);
      float a = r[0], b = r[1], d = r[2];
      mv = fmaxf(mv, fmaxf(fmaxf(a,b),d));
      av += a+b+d;
    }
    pmax[ob] = f2bf(mv);
    pavg[ob] = f2bf(av*(1.0f/9.0f));
  } else {
    int tl = blockIdx.x - PBLK;               // 0..99
    int j0 = (tl/10)*32, i0 = (tl%10)*32;     // <= 288
    const ushort* s = xpbf + (size_t)c*NPB;
    ushort*       d = bft  + (size_t)c*NPB;
    int tx = tid & 31, ty = tid >> 5;         // 32 x 8
    #pragma unroll
    for (int k=0;k<4;k++){
      int jj = ty + k*8;
      t[jj][tx] = s[(size_t)(j0+jj)*BSTR + (i0+tx)];
    }
    __syncthreads();
    #pragma unroll
    for (int k=0;k<4;k++){
      int ii = ty + k*8;
      d[(size_t)(i0+ii)*BSTR + (j0+tx)] = t[tx][ii];
    }
  }
}

// ---------------- MFMA matmul core (branch-free staging, BK=64 + 32 tail) ---
#define MM_PROLOGUE()                                                          \
  int tid = threadIdx.x;                                                       \
  int lane = tid & 63, wv = tid >> 6;                                          \
  int wr = (wv >> 1)*32, wc = (wv & 1)*32;                                     \
  int rowBase = blockIdx.x*64, colBase = blockIdx.y*64;                        \
  int l15 = lane & 15, lq = lane >> 4;                                         \
  f32x4 acc00 = {0.f,0.f,0.f,0.f}, acc01 = acc00, acc10 = acc00, acc11 = acc00;\
  int srow = tid >> 3, sc8 = tid & 7;

#define MM_MFMA_HALF(KK)                                                       \
  {                                                                            \
    bf16x8 a0 = __builtin_bit_cast(bf16x8, *(const ushort8*)(&As[(wr      + l15)*72 + (KK) + lq*8])); \
    bf16x8 a1 = __builtin_bit_cast(bf16x8, *(const ushort8*)(&As[(wr + 16 + l15)*72 + (KK) + lq*8])); \
    bf16x8 b0 = __builtin_bit_cast(bf16x8, *(const ushort8*)(&Bs[(wc      + l15)*72 + (KK) + lq*8])); \
    bf16x8 b1 = __builtin_bit_cast(bf16x8, *(const ushort8*)(&Bs[(wc + 16 + l15)*72 + (KK) + lq*8])); \
    acc00 = __builtin_amdgcn_mfma_f32_16x16x32_bf16(a0, b0, acc00, 0, 0, 0);   \
    acc01 = __builtin_amdgcn_mfma_f32_16x16x32_bf16(a0, b1, acc01, 0, 0, 0);   \
    acc10 = __builtin_amdgcn_mfma_f32_16x16x32_bf16(a1, b0, acc10, 0, 0, 0);   \
    acc11 = __builtin_amdgcn_mfma_f32_16x16x32_bf16(a1, b1, acc11, 0, 0, 0);   \
  }

// --- joint mm store: z<30 opening (Aop->Cop), z>=30 dilation (Adil->Cdil + colpart)
__global__ __launch_bounds__(256) void mm_joint_store_k(const ushort* __restrict__ Aop,
                                                        const ushort* __restrict__ Adil,
                                                        const ushort* __restrict__ BT,
                                                        float* __restrict__ Cop,
                                                        float* __restrict__ Cdil,
                                                        float* __restrict__ colpart){
  __shared__ ushort As[64*72];
  __shared__ ushort Bs[64*72];
  __shared__ float colred[8*64];
  int z = blockIdx.z;
  bool dil = (z >= C30);
  int ch = dil ? z - C30 : z;
  MM_PROLOGUE();
  const ushort* Ab = (dil ? Adil : Aop) + (size_t)ch*NPB + (size_t)rowBase*BSTR;
  const ushort* Bb = BT + (size_t)ch*NPB + (size_t)colBase*BSTR;
  const ushort* apt = Ab + (size_t)srow*BSTR + sc8*8;
  const ushort* bpt = Bb + (size_t)srow*BSTR + sc8*8;
  float*        Cb = (dil ? Cdil : Cop) + (size_t)ch*NPIX;
  for (int k0 = 0; k0 < 256; k0 += 64){
    *(ushort8*)(&As[srow*72 + sc8*8])      = *(const ushort8*)(apt + k0);
    *(ushort8*)(&As[(srow+32)*72 + sc8*8]) = *(const ushort8*)(apt + (size_t)32*BSTR + k0);
    *(ushort8*)(&Bs[srow*72 + sc8*8])      = *(const ushort8*)(bpt + k0);
    *(ushort8*)(&Bs[(srow+32)*72 + sc8*8]) = *(const ushort8*)(bpt + (size_t)32*BSTR + k0);
    __syncthreads();
    MM_MFMA_HALF(0);
    MM_MFMA_HALF(32);
    __syncthreads();
  }
  {  // tail k=256..287 (zero pad beyond 258)
    int row4 = tid >> 2, c84 = tid & 3;
    *(ushort8*)(&As[row4*72 + c84*8]) = *(const ushort8*)(Ab + (size_t)row4*BSTR + 256 + c84*8);
    *(ushort8*)(&Bs[row4*72 + c84*8]) = *(const ushort8*)(Bb + (size_t)row4*BSTR + 256 + c84*8);
    __syncthreads();
    MM_MFMA_HALF(0);
  }
  auto store = [&](f32x4 v, int r0, int c0){
    if (c0 < HP){
      #pragma unroll
      for (int r=0;r<4;r++){
        int rr = r0 + r;
        if (rr < HP) Cb[(size_t)rr*HP + c0] = v[r];
      }
    }
  };
  store(acc00, rowBase + wr +      lq*4, colBase + wc +      l15);
  store(acc01, rowBase + wr +      lq*4, colBase + wc + 16 + l15);
  store(acc10, rowBase + wr + 16 + lq*4, colBase + wc +      l15);
  store(acc11, rowBase + wr + 16 + lq*4, colBase + wc + 16 + l15);
  if (dil){
    __syncthreads();
    int slot = (wv>>1)*4 + lq;
    float s0 = 0.0f, s1 = 0.0f;
    #pragma unroll
    for (int r=0;r<4;r++){ s0 += acc00[r] + acc10[r]; s1 += acc01[r] + acc11[r]; }
    colred[slot*64 + wc +      l15] = s0;
    colred[slot*64 + wc + 16 + l15] = s1;
    __syncthreads();
    if (tid < 64){
      float cs = 0.0f;
      #pragma unroll
      for (int s=0;s<8;s++) cs += colred[s*64 + tid];
      colpart[((size_t)ch*5 + blockIdx.x)*320 + colBase + tid] = cs;
    }
  }
}

// --- joint mm absred: z<30 opening (A=An, B=-XP, op=-XP), z>=30 dilation ----
__global__ __launch_bounds__(256) void mm_joint_abs_k(const ushort* __restrict__ Aop,
                                                      const ushort* __restrict__ Adil,
                                                      const ushort* __restrict__ BT,
                                                      const float* __restrict__ XPop,
                                                      double* __restrict__ part){
  __shared__ ushort As[64*72];
  __shared__ ushort Bs[64*72];
  __shared__ double red[256];
  int z = blockIdx.z;
  bool negb = (z < C30);
  int ch = negb ? z : z - C30;
  MM_PROLOGUE();
  const ushort* Ab = (negb ? Aop : Adil) + (size_t)ch*NPB + (size_t)rowBase*BSTR;
  const ushort* Bb = BT + (size_t)ch*NPB + (size_t)colBase*BSTR;
  const ushort* apt = Ab + (size_t)srow*BSTR + sc8*8;
  const ushort* bpt = Bb + (size_t)srow*BSTR + sc8*8;
  const float*  Ob = XPop + (size_t)ch*NPIX;
  ushort one = f2bf(1.0f);
  auto fixB = [&](ushort8 t8, int brow, int kbase)->ushort8{
    if (!negb) return t8;
    if (brow >= HP) return t8;
    #pragma unroll
    for (int i=0;i<8;i++){
      int kk = kbase + i;
      if (kk < HP)
        t8[i] = (brow==0 || brow==HP-1 || kk==0 || kk==HP-1) ? one : (ushort)(t8[i] ^ 0x8000);
    }
    return t8;
  };
  for (int k0 = 0; k0 < 256; k0 += 64){
    *(ushort8*)(&As[srow*72 + sc8*8])      = *(const ushort8*)(apt + k0);
    *(ushort8*)(&As[(srow+32)*72 + sc8*8]) = *(const ushort8*)(apt + (size_t)32*BSTR + k0);
    *(ushort8*)(&Bs[srow*72 + sc8*8])      = fixB(*(const ushort8*)(bpt + k0), colBase + srow, k0 + sc8*8);
    *(ushort8*)(&Bs[(srow+32)*72 + sc8*8]) = fixB(*(const ushort8*)(bpt + (size_t)32*BSTR + k0), colBase + srow + 32, k0 + sc8*8);
    __syncthreads();
    MM_MFMA_HALF(0);
    MM_MFMA_HALF(32);
    __syncthreads();
  }
  {
    int row4 = tid >> 2, c84 = tid & 3;
    *(ushort8*)(&As[row4*72 + c84*8]) = *(const ushort8*)(Ab + (size_t)row4*BSTR + 256 + c84*8);
    *(ushort8*)(&Bs[row4*72 + c84*8]) = fixB(*(const ushort8*)(Bb + (size_t)row4*BSTR + 256 + c84*8), colBase + row4, 256 + c84*8);
    __syncthreads();
    MM_MFMA_HALF(0);
  }
  double local = 0.0;
  auto addq = [&](f32x4 v, int r0, int c0){
    if (c0 < HP){
      #pragma unroll
      for (int r=0;r<4;r++){
        int rr = r0 + r;
        if (rr < HP){
          float o = Ob[(size_t)rr*HP + c0];
          if (negb) o = (rr==0||rr==HP-1||c0==0||c0==HP-1) ? 1.0f : -o;
          local += (double)fabsf(o - v[r]);
        }
      }
    }
  };
  addq(acc00, rowBase + wr +      lq*4, colBase + wc +      l15);
  addq(acc01, rowBase + wr +      lq*4, colBase + wc + 16 + l15);
  addq(acc10, rowBase + wr + 16 + lq*4, colBase + wc +      l15);
  addq(acc11, rowBase + wr + 16 + lq*4, colBase + wc + 16 + l15);
  red[tid] = local;
  __syncthreads();
  for (int s=128; s>0; s>>=1){ if (tid<s) red[tid]+=red[tid+s]; __syncthreads(); }
  if (tid==0) part[(size_t)z*25 + blockIdx.y*5 + blockIdx.x] = red[0];
}

// ------- cm[c][w] = (sum_bx colpart_y - colsum x)/258 -----------------------
__global__ void cmcomb_k(const float* __restrict__ colpart, const float* __restrict__ xsrc,
                         float* __restrict__ cm){
  int c = blockIdx.y;
  int w = blockIdx.x*256 + threadIdx.x;
  if (w >= HP) return;
  const float* xb = xsrc + (size_t)c*NPIX;
  float xs = 0.0f;
  for (int r=0;r<HP;r++) xs += xb[(size_t)r*HP + w];
  float ys = 0.0f;
  #pragma unroll
  for (int bx=0;bx<5;bx++) ys += colpart[((size_t)c*5 + bx)*320 + w];
  cm[c*HP + w] = (ys - xs) / (float)HP;
}

// --- fused: [bx<PBLK] maxpool(F1)->BF0 | [else] rect+avgpool -> X1, BF2 -----
__global__ void poolrect_k(const float* __restrict__ F1, ushort* __restrict__ pmaxo,
                           const float* __restrict__ x, const float* __restrict__ y,
                           const float* __restrict__ cm,
                           float* __restrict__ x1, ushort* __restrict__ pavgo){
  __shared__ float rect[34][35];
  int c = blockIdx.y;
  int tid = threadIdx.x;
  if (blockIdx.x < PBLK){
    int p = blockIdx.x*256 + tid;
    if (p >= PTOT) return;
    int h = p / BSTR, w = p % BSTR;
    size_t ob = (size_t)c*NPB + p;
    if (h >= HP || w >= HP){ pmaxo[ob] = 0; return; }
    if (h==0 || h==HP-1 || w==0 || w==HP-1){ pmaxo[ob] = f2bf(1.0f); return; }
    const float* s = F1 + (size_t)c*NPIX;
    float mv = -3.402823466e+38f;
    #pragma unroll
    for (int dy=-1;dy<=1;dy++){
      const float* r = s + (size_t)(h+dy)*HP + (w-1);
      mv = fmaxf(mv, fmaxf(fmaxf(r[0],r[1]),r[2]));
    }
    pmaxo[ob] = f2bf(mv);
  } else {
    int tl = blockIdx.x - PBLK;               // 0..109
    int c0 = (tl/10)*32, r0 = (tl%10)*32;
    const float* xb = x + (size_t)c*NPIX;
    const float* yb = y + (size_t)c*NPIX;
    for (int idx = tid; idx < 34*34; idx += 256){
      int lr = idx/34, lc = idx%34;
      int h = r0 - 1 + lr, w = c0 - 1 + lc;
      float v = 0.0f;
      if (h >= 0 && h < HP && w >= 0 && w < HP){
        float xv = xb[(size_t)h*HP + w];
        float off = yb[(size_t)h*HP + w] - xv - cm[c*HP + w];
        v = xv + fmaxf(off, 0.0f);
      }
      rect[lr][lc] = v;
    }
    __syncthreads();
    for (int idx = tid; idx < 32*32; idx += 256){
      int lr = idx/32, lc = idx%32;
      int h = r0 + lr, w = c0 + lc;
      if (w >= BSTR || h >= RPAD) continue;
      bool vpix = (h < HP && w < HP);
      if (vpix) x1[(size_t)c*NPIX + (size_t)h*HP + w] = rect[lr+1][lc+1];
      ushort o;
      if (!vpix) o = 0;
      else if (h==0 || h==HP-1 || w==0 || w==HP-1) o = f2bf(1.0f);
      else {
        float av = (rect[lr][lc]   + rect[lr][lc+1]   + rect[lr][lc+2])
                 + (rect[lr+1][lc] + rect[lr+1][lc+1] + rect[lr+1][lc+2])
                 + (rect[lr+2][lc] + rect[lr+2][lc+1] + rect[lr+2][lc+2]);
        o = f2bf(av*(1.0f/9.0f));
      }
      pavgo[(size_t)c*NPB + (size_t)h*BSTR + w] = o;
    }
  }
}

// --- fused: [bx<PBLK] invnorm(F1)->BF1 | [else] rect+invnorm(X1,F2,cm)->BF0 -
__global__ void invrect_k(const float* __restrict__ oper, ushort* __restrict__ An,
                          const float* __restrict__ x, const float* __restrict__ y,
                          const float* __restrict__ cm, ushort* __restrict__ An2){
  bool second = (blockIdx.x >= PBLK);
  int p = (second ? blockIdx.x - PBLK : blockIdx.x)*256 + threadIdx.x;
  if (p >= PTOT) return;
  int h = p / BSTR, w = p % BSTR;
  ushort* dst = second ? An2 : An;
  if (h >= HP || w >= HP){
    #pragma unroll
    for (int c=0;c<C30;c++) dst[(size_t)c*NPB+p] = 0;
    return;
  }
  int pd = h*HP + w;
  float v[C30];
  float ss = 0.0f;
  if (!second){
    #pragma unroll
    for (int c=0;c<C30;c++){ v[c] = oper[(size_t)c*NPIX+pd]; ss = fmaf(v[c],v[c],ss); }
  } else {
    float cmv = cm[0*HP + w];  // overwritten per c below
    (void)cmv;
    #pragma unroll
    for (int c=0;c<C30;c++){
      float xv = x[(size_t)c*NPIX + pd];
      float off = y[(size_t)c*NPIX + pd] - xv - cm[c*HP + w];
      float vv = xv + fmaxf(off, 0.0f);
      v[c] = vv;
      ss = fmaf(vv, vv, ss);
    }
  }
  float n = sqrtf(2.0f*ss);
  float inv = 1.0f / fmaxf(n, 1e-12f);
  #pragma unroll
  for (int c=0;c<C30;c++) dst[(size_t)c*NPB+p] = f2bf(v[c]*inv);
}

// ---------------- final: |2*(S0 - S1)| + base_loss --------------------------
__global__ void finalize_k(const double* __restrict__ part,
                           const float* __restrict__ base, float* __restrict__ out){
  __shared__ double s0[256], s1[256];
  int tid = threadIdx.x;
  double l0=0.0, l1=0.0;
  for (int i=tid;i<750;i+=256){ l0 += part[i]; l1 += part[750+i]; }
  s0[tid]=l0; s1[tid]=l1; __syncthreads();
  for (int s=128;s>0;s>>=1){ if (tid<s){ s0[tid]+=s0[tid+s]; s1[tid]+=s1[tid+s]; } __syncthreads(); }
  if (tid==0){
    out[0] = (float)(fabs(2.0*(s0[0]-s1[0])) + (double)base[0]);
  }
}

extern "C" void kernel_launch(void* const* d_in, const int* in_sizes, int n_in,
                              void* d_out, int out_size, void* d_ws, size_t ws_size,
                              hipStream_t stream){
  const float* logits = (const float*)d_in[0];
  const float* base   = (const float*)d_in[1];
  float* out = (float*)d_out;

  char* ws = (char*)d_ws;
  size_t off = 0;
  auto alloc = [&](size_t bytes)->char*{
    char* p = ws + off; off = (off + bytes + 255) & ~(size_t)255; return p;
  };
  double* part    = (double*)alloc(1500*sizeof(double));
  float*  cm      = (float*) alloc((size_t)C30*HP*sizeof(float));
  float*  colpart = (float*) alloc((size_t)C30*5*320*sizeof(float));
  float*  XP      = (float*) alloc((size_t)TOT*sizeof(float));
  ushort* BF0     = (ushort*)alloc((size_t)C30*NPB*sizeof(ushort)); // xpbf -> pooled C1 -> An2
  ushort* BFT     = (ushort*)alloc((size_t)C30*NPB*sizeof(ushort));
  ushort* BF1     = (ushort*)alloc((size_t)C30*NPB*sizeof(ushort)); // maxpool -> An
  ushort* BF2     = (ushort*)alloc((size_t)C30*NPB*sizeof(ushort)); // avgpool -> pool(x1)
  float*  F1      = (float*) alloc((size_t)TOT*sizeof(float));      // opening fp32 stream
  float*  F2      = (float*) alloc((size_t)TOT*sizeof(float));      // dilation fp32 stream
  float*  X1      = (float*) alloc((size_t)TOT*sizeof(float));
  (void)ws_size; (void)in_sizes; (void)n_in; (void)out_size;

  dim3 mmGrid(5, 5, 2*C30);                      // joint: z<30 opening, z>=30 dilation
  dim3 tpGrid(PBLK + 100, C30);                  // pool_both + transpose
  dim3 prGrid(PBLK + 110, C30);                  // pool_max + rect_pool
  dim3 cmGrid((HP+255)/256, C30);
  int pb = PBLK;

  build_fc_k<<<pb,256,0,stream>>>(logits, XP, BF0);
  trpool_k<<<tpGrid,256,0,stream>>>(BF0, BFT, XP, BF1, BF2);

  // step 1 (both branches): C1 = maxpool@XP ; y1 = avgpool@XP + colsums
  mm_joint_store_k<<<mmGrid,256,0,stream>>>(BF1, BF2, BFT, F1, F2, colpart);
  cmcomb_k<<<cmGrid,256,0,stream>>>(colpart, XP, cm);
  poolrect_k<<<prGrid,256,0,stream>>>(F1, BF0, XP, F2, cm, X1, BF2);

  // step 2: O2 = pool(C1)@XP ; y2 = pool(x1)@XP + colsums
  mm_joint_store_k<<<mmGrid,256,0,stream>>>(BF0, BF2, BFT, F1, F2, colpart);
  cmcomb_k<<<cmGrid,256,0,stream>>>(colpart, X1, cm);
  invrect_k<<<2*PBLK,256,0,stream>>>(F1, BF1, X1, F2, cm, BF0);

  // final joint matmul + abs-reduce
  mm_joint_abs_k<<<mmGrid,256,0,stream>>>(BF1, BF0, BFT, XP, part);
  finalize_k<<<1,256,0,stream>>>(part, base, out);
}

// Round 9
// 163.684 us; speedup vs baseline: 1.1401x; 1.0197x over previous
//
#include <hip/hip_runtime.h>
#include <math.h>

#define HP 258
#define RPAD 320              // padded rows for bf16 operand buffers
#define BSTR 328              // bf16 row stride (656B, 16B-aligned)
#define NPIX (HP*HP)          // 66564
#define NPB  (RPAD*BSTR)      // 104960 bf16 elems per channel
#define PTOT (RPAD*BSTR)
#define C30 30
#define TOT (C30*NPIX)
#define LOGW 64
#define PBLK 410              // ceil(PTOT/256)
#define CH 3                  // channels per buildall block

typedef __bf16 bf16x8 __attribute__((ext_vector_type(8)));
typedef float  f32x4  __attribute__((ext_vector_type(4)));
typedef unsigned short ushort;
typedef unsigned short ushort8 __attribute__((ext_vector_type(8)));

static __device__ inline ushort f2bf(float f){
  __bf16 h = (__bf16)f;
  return __builtin_bit_cast(ushort, h);
}
static __device__ inline float bf2f(ushort u){
  return (float)__builtin_bit_cast(__bf16, u);
}

// ---- buildall: softmax+fc+XP+BFT(transposed)+maxpool+avgpool+col partials --
// grid (100 tiles, 10 chunks of 3 channels), 256 threads.
__global__ __launch_bounds__(256) void buildall_k(const float* __restrict__ logits,
    float* __restrict__ XP, ushort* __restrict__ BFT,
    ushort* __restrict__ BF1, ushort* __restrict__ BF2,
    float* __restrict__ xpart, float* __restrict__ apart){
  __shared__ float s6[6][34][35];
  __shared__ float fcb[34][35];
  __shared__ ushort tbuf[32][33];
  __shared__ float cr[2][8][33];
  int tile = blockIdx.x;                 // 0..99
  int tr = tile/10, tc = tile%10;
  int r0 = tr*32, c0 = tc*32;
  int tid = threadIdx.x;
  // 1) softmax on halo (only where fc is needed: h,w in [1,256])
  for (int idx = tid; idx < 34*34; idx += 256){
    int lr = idx/34, lc = idx%34;
    int h = r0 - 1 + lr, w = c0 - 1 + lc;
    float sv[6];
    if (h >= 1 && h <= 256 && w >= 1 && w <= 256){
      int oh = h-1, ow = w-1;
      float fy = 0.25f*oh - 0.375f;
      float fx = 0.25f*ow - 0.375f;
      float y0f = floorf(fy), x0f = floorf(fx);
      float ty = fy - y0f, tx2 = fx - x0f;
      int y0 = max(0, (int)y0f), y1 = min(LOGW-1, (int)y0f + 1);
      int x0 = max(0, (int)x0f), x1 = min(LOGW-1, (int)x0f + 1);
      float m = -3.402823466e+38f;
      #pragma unroll
      for (int c=0;c<6;c++){
        const float* pl = logits + c*LOGW*LOGW;
        float v00 = pl[y0*LOGW + x0], v01 = pl[y0*LOGW + x1];
        float v10 = pl[y1*LOGW + x0], v11 = pl[y1*LOGW + x1];
        float a = v00 + (v01 - v00)*tx2;
        float b = v10 + (v11 - v10)*tx2;
        float v = a + (b - a)*ty;
        sv[c] = v; m = fmaxf(m, v);
      }
      float sum = 0.0f;
      #pragma unroll
      for (int c=0;c<6;c++){ sv[c] = expf(sv[c]-m); sum += sv[c]; }
      float inv = 1.0f/sum;
      #pragma unroll
      for (int c=0;c<6;c++) sv[c] *= inv;
    } else {
      #pragma unroll
      for (int c=0;c<6;c++) sv[c] = 0.0f;
    }
    #pragma unroll
    for (int c=0;c<6;c++) s6[c][lr][lc] = sv[c];
  }
  __syncthreads();
  int tx = tid & 31, rg = tid >> 5;
  for (int cc=0; cc<CH; cc++){
    int ci = blockIdx.y*CH + cc;
    int i = ci/5, r = ci%5;
    int j = r + (r>=i ? 1 : 0);
    // 2) fcb = XPval on halo (pad 0 / border 1 / interior fc)
    for (int idx = tid; idx < 34*34; idx += 256){
      int lr = idx/34, lc = idx%34;
      int h = r0 - 1 + lr, w = c0 - 1 + lc;
      float v;
      if (h < 0 || h >= HP || w < 0 || w >= HP) v = 0.0f;
      else if (h==0 || h==HP-1 || w==0 || w==HP-1) v = 1.0f;
      else v = fmaxf(0.5f*(s6[i][lr][lc] - s6[j][lr][lc]), 0.0f);
      fcb[lr][lc] = v;
    }
    __syncthreads();
    // 3) per-pixel outputs
    float xs_acc = 0.0f, as_acc = 0.0f;
    #pragma unroll
    for (int kk=0; kk<4; kk++){
      int lrow = rg + 8*kk;              // 0..31
      int h = r0 + lrow, w = c0 + tx;
      int lr = lrow + 1, lc = tx + 1;
      float xpv = fcb[lr][lc];
      ushort pmaxv, pavgv, xbfv;
      if (h >= HP || w >= HP){ pmaxv = 0; pavgv = 0; xbfv = 0; }
      else if (h==0 || h==HP-1 || w==0 || w==HP-1){
        pmaxv = f2bf(1.0f); pavgv = pmaxv; xbfv = pmaxv;
        XP[(size_t)ci*NPIX + (size_t)h*HP + w] = 1.0f;
        xs_acc += 1.0f;
        as_acc += 1.0f;
      } else {
        float mv = -3.402823466e+38f, av = 0.0f;
        #pragma unroll
        for (int dy=-1;dy<=1;dy++)
          #pragma unroll
          for (int dx=-1;dx<=1;dx++){
            float nv = fcb[lr+dy][lc+dx];
            mv = fmaxf(mv, nv); av += nv;
          }
        pmaxv = f2bf(mv);
        pavgv = f2bf(av*(1.0f/9.0f));
        xbfv  = f2bf(xpv);
        XP[(size_t)ci*NPIX + (size_t)h*HP + w] = xpv;
        xs_acc += xpv;
        as_acc += bf2f(pavgv);
      }
      size_t ob = (size_t)ci*NPB + (size_t)h*BSTR + w;
      BF1[ob] = pmaxv;
      BF2[ob] = pavgv;
      tbuf[lrow][tx] = xbfv;
    }
    cr[0][rg][tx] = xs_acc;
    cr[1][rg][tx] = as_acc;
    __syncthreads();
    if (tid < 32){
      float xs = 0.0f, as = 0.0f;
      #pragma unroll
      for (int g=0; g<8; g++){ xs += cr[0][g][tid]; as += cr[1][g][tid]; }
      xpart[((size_t)ci*10 + tr)*320 + c0 + tid] = xs;
      apart[((size_t)ci*10 + tr)*320 + c0 + tid] = as;
    }
    // transpose write: BFT[(c0+a)*BSTR + (r0+b)] = tbuf[b][a]
    #pragma unroll
    for (int kk=0; kk<4; kk++){
      int a = rg + 8*kk;
      BFT[(size_t)ci*NPB + (size_t)(c0+a)*BSTR + (r0 + tx)] = tbuf[tx][a];
    }
    __syncthreads();
  }
}

// ---------------- MFMA matmul core (branch-free staging, BK=64 + 32 tail) ---
#define MM_PROLOGUE()                                                          \
  int tid = threadIdx.x;                                                       \
  int lane = tid & 63, wv = tid >> 6;                                          \
  int wr = (wv >> 1)*32, wc = (wv & 1)*32;                                     \
  int rowBase = blockIdx.x*64, colBase = blockIdx.y*64;                        \
  int l15 = lane & 15, lq = lane >> 4;                                         \
  f32x4 acc00 = {0.f,0.f,0.f,0.f}, acc01 = acc00, acc10 = acc00, acc11 = acc00;\
  int srow = tid >> 3, sc8 = tid & 7;

#define MM_MFMA_HALF(KK)                                                       \
  {                                                                            \
    bf16x8 a0 = __builtin_bit_cast(bf16x8, *(const ushort8*)(&As[(wr      + l15)*72 + (KK) + lq*8])); \
    bf16x8 a1 = __builtin_bit_cast(bf16x8, *(const ushort8*)(&As[(wr + 16 + l15)*72 + (KK) + lq*8])); \
    bf16x8 b0 = __builtin_bit_cast(bf16x8, *(const ushort8*)(&Bs[(wc      + l15)*72 + (KK) + lq*8])); \
    bf16x8 b1 = __builtin_bit_cast(bf16x8, *(const ushort8*)(&Bs[(wc + 16 + l15)*72 + (KK) + lq*8])); \
    acc00 = __builtin_amdgcn_mfma_f32_16x16x32_bf16(a0, b0, acc00, 0, 0, 0);   \
    acc01 = __builtin_amdgcn_mfma_f32_16x16x32_bf16(a0, b1, acc01, 0, 0, 0);   \
    acc10 = __builtin_amdgcn_mfma_f32_16x16x32_bf16(a1, b0, acc10, 0, 0, 0);   \
    acc11 = __builtin_amdgcn_mfma_f32_16x16x32_bf16(a1, b1, acc11, 0, 0, 0);   \
  }

// --- joint mm store + cm blocks: z<30 op, 30..59 dil, z>=60 cm matvec -------
__global__ __launch_bounds__(256) void mm_joint_store_k(const ushort* __restrict__ Aop,
                                                        const ushort* __restrict__ Adil,
                                                        const ushort* __restrict__ BT,
                                                        float* __restrict__ Cop,
                                                        float* __restrict__ Cdil,
                                                        const float* __restrict__ XPd,
                                                        const float* __restrict__ apart_,
                                                        const float* __restrict__ xpart_,
                                                        float* __restrict__ cmo){
  __shared__ ushort As[64*72];
  __shared__ ushort Bs[64*72];
  int z = blockIdx.z;
  if (z >= 2*C30){
    // cm block: cm[ch][w] = ((colsum A) @ XP - colsum x)/258
    int lin = blockIdx.y*5 + blockIdx.x;
    int ch = (z - 2*C30)*25 + lin;
    if (ch >= C30) return;
    float* colA = (float*)As;          // 258 floats
    const float* ap = apart_ + (size_t)ch*10*320;
    for (int k = threadIdx.x; k < HP; k += 256){
      float s = 0.0f;
      #pragma unroll
      for (int t=0;t<10;t++) s += ap[t*320 + k];
      colA[k] = s;
    }
    __syncthreads();
    const float* xpd = XPd + (size_t)ch*NPIX;
    const float* xp2 = xpart_ + (size_t)ch*10*320;
    for (int w = threadIdx.x; w < HP; w += 256){
      float acc = 0.0f;
      for (int k=0;k<HP;k++) acc = fmaf(colA[k], xpd[(size_t)k*HP + w], acc);
      float xs = 0.0f;
      #pragma unroll
      for (int t=0;t<10;t++) xs += xp2[t*320 + w];
      cmo[ch*HP + w] = (acc - xs) * (1.0f/(float)HP);
    }
    return;
  }
  bool dil = (z >= C30);
  int ch = dil ? z - C30 : z;
  MM_PROLOGUE();
  const ushort* Ab = (dil ? Adil : Aop) + (size_t)ch*NPB + (size_t)rowBase*BSTR;
  const ushort* Bb = BT + (size_t)ch*NPB + (size_t)colBase*BSTR;
  const ushort* apt = Ab + (size_t)srow*BSTR + sc8*8;
  const ushort* bpt = Bb + (size_t)srow*BSTR + sc8*8;
  float*        Cb = (dil ? Cdil : Cop) + (size_t)ch*NPIX;
  for (int k0 = 0; k0 < 256; k0 += 64){
    *(ushort8*)(&As[srow*72 + sc8*8])      = *(const ushort8*)(apt + k0);
    *(ushort8*)(&As[(srow+32)*72 + sc8*8]) = *(const ushort8*)(apt + (size_t)32*BSTR + k0);
    *(ushort8*)(&Bs[srow*72 + sc8*8])      = *(const ushort8*)(bpt + k0);
    *(ushort8*)(&Bs[(srow+32)*72 + sc8*8]) = *(const ushort8*)(bpt + (size_t)32*BSTR + k0);
    __syncthreads();
    MM_MFMA_HALF(0);
    MM_MFMA_HALF(32);
    __syncthreads();
  }
  {  // tail k=256..287 (zero pad beyond 258)
    int row4 = tid >> 2, c84 = tid & 3;
    *(ushort8*)(&As[row4*72 + c84*8]) = *(const ushort8*)(Ab + (size_t)row4*BSTR + 256 + c84*8);
    *(ushort8*)(&Bs[row4*72 + c84*8]) = *(const ushort8*)(Bb + (size_t)row4*BSTR + 256 + c84*8);
    __syncthreads();
    MM_MFMA_HALF(0);
  }
  auto store = [&](f32x4 v, int r0, int c0){
    if (c0 < HP){
      #pragma unroll
      for (int r=0;r<4;r++){
        int rr = r0 + r;
        if (rr < HP) Cb[(size_t)rr*HP + c0] = v[r];
      }
    }
  };
  store(acc00, rowBase + wr +      lq*4, colBase + wc +      l15);
  store(acc01, rowBase + wr +      lq*4, colBase + wc + 16 + l15);
  store(acc10, rowBase + wr + 16 + lq*4, colBase + wc +      l15);
  store(acc11, rowBase + wr + 16 + lq*4, colBase + wc + 16 + l15);
}

// --- joint mm absred: z<30 opening (negB), z>=30 dilation -------------------
__global__ __launch_bounds__(256) void mm_joint_abs_k(const ushort* __restrict__ Aop,
                                                      const ushort* __restrict__ Adil,
                                                      const ushort* __restrict__ BT,
                                                      const float* __restrict__ XPop,
                                                      double* __restrict__ part){
  __shared__ ushort As[64*72];
  __shared__ ushort Bs[64*72];
  __shared__ double red[256];
  int z = blockIdx.z;
  bool negb = (z < C30);
  int ch = negb ? z : z - C30;
  MM_PROLOGUE();
  const ushort* Ab = (negb ? Aop : Adil) + (size_t)ch*NPB + (size_t)rowBase*BSTR;
  const ushort* Bb = BT + (size_t)ch*NPB + (size_t)colBase*BSTR;
  const ushort* apt = Ab + (size_t)srow*BSTR + sc8*8;
  const ushort* bpt = Bb + (size_t)srow*BSTR + sc8*8;
  const float*  Ob = XPop + (size_t)ch*NPIX;
  ushort one = f2bf(1.0f);
  auto fixB = [&](ushort8 t8, int brow, int kbase)->ushort8{
    if (!negb) return t8;
    if (brow >= HP) return t8;
    #pragma unroll
    for (int i=0;i<8;i++){
      int kk = kbase + i;
      if (kk < HP)
        t8[i] = (brow==0 || brow==HP-1 || kk==0 || kk==HP-1) ? one : (ushort)(t8[i] ^ 0x8000);
    }
    return t8;
  };
  for (int k0 = 0; k0 < 256; k0 += 64){
    *(ushort8*)(&As[srow*72 + sc8*8])      = *(const ushort8*)(apt + k0);
    *(ushort8*)(&As[(srow+32)*72 + sc8*8]) = *(const ushort8*)(apt + (size_t)32*BSTR + k0);
    *(ushort8*)(&Bs[srow*72 + sc8*8])      = fixB(*(const ushort8*)(bpt + k0), colBase + srow, k0 + sc8*8);
    *(ushort8*)(&Bs[(srow+32)*72 + sc8*8]) = fixB(*(const ushort8*)(bpt + (size_t)32*BSTR + k0), colBase + srow + 32, k0 + sc8*8);
    __syncthreads();
    MM_MFMA_HALF(0);
    MM_MFMA_HALF(32);
    __syncthreads();
  }
  {
    int row4 = tid >> 2, c84 = tid & 3;
    *(ushort8*)(&As[row4*72 + c84*8]) = *(const ushort8*)(Ab + (size_t)row4*BSTR + 256 + c84*8);
    *(ushort8*)(&Bs[row4*72 + c84*8]) = fixB(*(const ushort8*)(Bb + (size_t)row4*BSTR + 256 + c84*8), colBase + row4, 256 + c84*8);
    __syncthreads();
    MM_MFMA_HALF(0);
  }
  double local = 0.0;
  auto addq = [&](f32x4 v, int r0, int c0){
    if (c0 < HP){
      #pragma unroll
      for (int r=0;r<4;r++){
        int rr = r0 + r;
        if (rr < HP){
          float o = Ob[(size_t)rr*HP + c0];
          if (negb) o = (rr==0||rr==HP-1||c0==0||c0==HP-1) ? 1.0f : -o;
          local += (double)fabsf(o - v[r]);
        }
      }
    }
  };
  addq(acc00, rowBase + wr +      lq*4, colBase + wc +      l15);
  addq(acc01, rowBase + wr +      lq*4, colBase + wc + 16 + l15);
  addq(acc10, rowBase + wr + 16 + lq*4, colBase + wc +      l15);
  addq(acc11, rowBase + wr + 16 + lq*4, colBase + wc + 16 + l15);
  red[tid] = local;
  __syncthreads();
  for (int s=128; s>0; s>>=1){ if (tid<s) red[tid]+=red[tid+s]; __syncthreads(); }
  if (tid==0) part[(size_t)z*25 + blockIdx.y*5 + blockIdx.x] = red[0];
}

// --- fused: [bx<PBLK] maxpool(F1)->BF0 | [else] rect+avgpool + partials -----
__global__ void poolrect_k(const float* __restrict__ F1, ushort* __restrict__ pmaxo,
                           const float* __restrict__ x, const float* __restrict__ y,
                           const float* __restrict__ cm,
                           float* __restrict__ x1, ushort* __restrict__ pavgo,
                           float* __restrict__ x1part, float* __restrict__ a2part){
  __shared__ float rect[34][35];
  __shared__ float cr[2][8][33];
  int ci = blockIdx.y;
  int tid = threadIdx.x;
  if (blockIdx.x < PBLK){
    int p = blockIdx.x*256 + tid;
    if (p >= PTOT) return;
    int h = p / BSTR, w = p % BSTR;
    size_t ob = (size_t)ci*NPB + p;
    if (h >= HP || w >= HP){ pmaxo[ob] = 0; return; }
    if (h==0 || h==HP-1 || w==0 || w==HP-1){ pmaxo[ob] = f2bf(1.0f); return; }
    const float* s = F1 + (size_t)ci*NPIX;
    float mv = -3.402823466e+38f;
    #pragma unroll
    for (int dy=-1;dy<=1;dy++){
      const float* rr = s + (size_t)(h+dy)*HP + (w-1);
      mv = fmaxf(mv, fmaxf(fmaxf(rr[0],rr[1]),rr[2]));
    }
    pmaxo[ob] = f2bf(mv);
    return;
  }
  int tl = blockIdx.x - PBLK;               // 0..99
  int tcx = tl/10, tty = tl%10;
  int c0 = tcx*32, r0 = tty*32;
  const float* xb = x + (size_t)ci*NPIX;
  const float* yb = y + (size_t)ci*NPIX;
  for (int idx = tid; idx < 34*34; idx += 256){
    int lr = idx/34, lc = idx%34;
    int h = r0 - 1 + lr, w = c0 - 1 + lc;
    float v = 0.0f;
    if (h >= 0 && h < HP && w >= 0 && w < HP){
      float xv = xb[(size_t)h*HP + w];
      float off = yb[(size_t)h*HP + w] - xv - cm[ci*HP + w];
      v = xv + fmaxf(off, 0.0f);
    }
    rect[lr][lc] = v;
  }
  __syncthreads();
  int tx = tid & 31, rg = tid >> 5;
  float xs_acc = 0.0f, as_acc = 0.0f;
  #pragma unroll
  for (int kk=0; kk<4; kk++){
    int lrow = rg + 8*kk;
    int h = r0 + lrow, w = c0 + tx;
    bool vpix = (h < HP && w < HP);
    ushort o;
    if (!vpix) o = 0;
    else {
      float xv = rect[lrow+1][tx+1];
      x1[(size_t)ci*NPIX + (size_t)h*HP + w] = xv;
      xs_acc += xv;
      if (h==0 || h==HP-1 || w==0 || w==HP-1){
        o = f2bf(1.0f);
        as_acc += 1.0f;
      } else {
        float av = (rect[lrow][tx]   + rect[lrow][tx+1]   + rect[lrow][tx+2])
                 + (rect[lrow+1][tx] + rect[lrow+1][tx+1] + rect[lrow+1][tx+2])
                 + (rect[lrow+2][tx] + rect[lrow+2][tx+1] + rect[lrow+2][tx+2]);
        o = f2bf(av*(1.0f/9.0f));
        as_acc += bf2f(o);
      }
    }
    if (h < RPAD && w < 320)
      pavgo[(size_t)ci*NPB + (size_t)h*BSTR + w] = o;
  }
  cr[0][rg][tx] = xs_acc;
  cr[1][rg][tx] = as_acc;
  __syncthreads();
  if (tid < 32){
    float xs = 0.0f, as = 0.0f;
    #pragma unroll
    for (int g=0; g<8; g++){ xs += cr[0][g][tid]; as += cr[1][g][tid]; }
    x1part[((size_t)ci*10 + tty)*320 + c0 + tid] = xs;
    a2part[((size_t)ci*10 + tty)*320 + c0 + tid] = as;
  }
}

// --- fused: [bx<PBLK] invnorm(F1)->An | [else] rect+invnorm(X1,F2,cm)->An2 --
__global__ void invrect_k(const float* __restrict__ oper, ushort* __restrict__ An,
                          const float* __restrict__ x, const float* __restrict__ y,
                          const float* __restrict__ cm, ushort* __restrict__ An2){
  bool second = (blockIdx.x >= PBLK);
  int p = (second ? blockIdx.x - PBLK : blockIdx.x)*256 + threadIdx.x;
  if (p >= PTOT) return;
  int h = p / BSTR, w = p % BSTR;
  ushort* dst = second ? An2 : An;
  if (h >= HP || w >= HP){
    #pragma unroll
    for (int c=0;c<C30;c++) dst[(size_t)c*NPB+p] = 0;
    return;
  }
  int pd = h*HP + w;
  float v[C30];
  float ss = 0.0f;
  if (!second){
    #pragma unroll
    for (int c=0;c<C30;c++){ v[c] = oper[(size_t)c*NPIX+pd]; ss = fmaf(v[c],v[c],ss); }
  } else {
    #pragma unroll
    for (int c=0;c<C30;c++){
      float xv = x[(size_t)c*NPIX + pd];
      float off = y[(size_t)c*NPIX + pd] - xv - cm[c*HP + w];
      float vv = xv + fmaxf(off, 0.0f);
      v[c] = vv;
      ss = fmaf(vv, vv, ss);
    }
  }
  float n = sqrtf(2.0f*ss);
  float inv = 1.0f / fmaxf(n, 1e-12f);
  #pragma unroll
  for (int c=0;c<C30;c++) dst[(size_t)c*NPB+p] = f2bf(v[c]*inv);
}

// ---------------- final: |2*(S0 - S1)| + base_loss --------------------------
__global__ void finalize_k(const double* __restrict__ part,
                           const float* __restrict__ base, float* __restrict__ out){
  __shared__ double s0[256], s1[256];
  int tid = threadIdx.x;
  double l0=0.0, l1=0.0;
  for (int i=tid;i<750;i+=256){ l0 += part[i]; l1 += part[750+i]; }
  s0[tid]=l0; s1[tid]=l1; __syncthreads();
  for (int s=128;s>0;s>>=1){ if (tid<s){ s0[tid]+=s0[tid+s]; s1[tid]+=s1[tid+s]; } __syncthreads(); }
  if (tid==0){
    out[0] = (float)(fabs(2.0*(s0[0]-s1[0])) + (double)base[0]);
  }
}

extern "C" void kernel_launch(void* const* d_in, const int* in_sizes, int n_in,
                              void* d_out, int out_size, void* d_ws, size_t ws_size,
                              hipStream_t stream){
  const float* logits = (const float*)d_in[0];
  const float* base   = (const float*)d_in[1];
  float* out = (float*)d_out;

  char* ws = (char*)d_ws;
  size_t off = 0;
  auto alloc = [&](size_t bytes)->char*{
    char* p = ws + off; off = (off + bytes + 255) & ~(size_t)255; return p;
  };
  double* part    = (double*)alloc(1500*sizeof(double));
  float*  cm      = (float*) alloc((size_t)C30*HP*sizeof(float));
  float*  xpart   = (float*) alloc((size_t)C30*10*320*sizeof(float));
  float*  apart   = (float*) alloc((size_t)C30*10*320*sizeof(float));
  float*  x1part  = (float*) alloc((size_t)C30*10*320*sizeof(float));
  float*  a2part  = (float*) alloc((size_t)C30*10*320*sizeof(float));
  float*  XP      = (float*) alloc((size_t)TOT*sizeof(float));
  ushort* BF0     = (ushort*)alloc((size_t)C30*NPB*sizeof(ushort)); // pool(C1) -> An2
  ushort* BFT     = (ushort*)alloc((size_t)C30*NPB*sizeof(ushort)); // XP^T bf16
  ushort* BF1     = (ushort*)alloc((size_t)C30*NPB*sizeof(ushort)); // maxpool -> An
  ushort* BF2     = (ushort*)alloc((size_t)C30*NPB*sizeof(ushort)); // avgpool -> pool(x1)
  float*  F1      = (float*) alloc((size_t)TOT*sizeof(float));      // opening fp32 stream
  float*  F2      = (float*) alloc((size_t)TOT*sizeof(float));      // dilation fp32 stream
  float*  X1      = (float*) alloc((size_t)TOT*sizeof(float));
  (void)ws_size; (void)in_sizes; (void)n_in; (void)out_size;

  dim3 mmGrid(5, 5, 2*C30 + 2);                  // +2 z-slices = 30 cm blocks
  dim3 mmAbsGrid(5, 5, 2*C30);
  dim3 baGrid(100, 10);                          // tiles x channel-chunks(3)
  dim3 prGrid(PBLK + 100, C30);

  // 1: softmax+fc+XP+BFT+pools+partials (reads only logits)
  buildall_k<<<baGrid,256,0,stream>>>(logits, XP, BFT, BF1, BF2, xpart, apart);
  // 2: C1 = maxpool@XP ; y1 = avgpool@XP ; cm1 (matvec blocks)
  mm_joint_store_k<<<mmGrid,256,0,stream>>>(BF1, BF2, BFT, F1, F2, XP, apart, xpart, cm);
  // 3: maxpool(C1) ; x1 = rect(XP,y1,cm1) + avgpool(x1) + partials
  poolrect_k<<<prGrid,256,0,stream>>>(F1, BF0, XP, F2, cm, X1, BF2, x1part, a2part);
  // 4: O2 = pool(C1)@XP ; y2 = pool(x1)@XP ; cm2
  mm_joint_store_k<<<mmGrid,256,0,stream>>>(BF0, BF2, BFT, F1, F2, XP, a2part, x1part, cm);
  // 5: An = invnorm(O2) ; An2 = invnorm(rect(x1,y2,cm2))
  invrect_k<<<2*PBLK,256,0,stream>>>(F1, BF1, X1, F2, cm, BF0);
  // 6: final joint matmul + abs-reduce
  mm_joint_abs_k<<<mmAbsGrid,256,0,stream>>>(BF1, BF0, BFT, XP, part);
  finalize_k<<<1,256,0,stream>>>(part, base, out);
}